// Round 16
// baseline (100.152 us; speedup 1.0000x reference)
//
#include <hip/hip_runtime.h>
#include <math.h>

#define NS 4
#define HDIM 1024
#define DDIM 4096           // NS*HDIM
#define TOK_B 16            // tokens per block (dots)
#define KCH 512             // K-chunk per block (8 chunks over K=4096)
#define NPS 32              // partial sets = 8 kc * 4 kh
#define HC_EPS_F 1e-6f
#define NORM_EPS_F 1e-6f

typedef __attribute__((ext_vector_type(8))) short short8;
typedef __attribute__((ext_vector_type(4))) float f32x4;

__device__ __forceinline__ float frcp(float v) { return __builtin_amdgcn_rcpf(v); }

__device__ __forceinline__ void gload_lds16(const float* g, float* l) {
  __builtin_amdgcn_global_load_lds(
      (const __attribute__((address_space(1))) void*)g,
      (__attribute__((address_space(3))) void*)l, 16, 0, 0);
}

// fp32 -> bf16 hi (truncate) + lo (residual). 3-term MFMA ~ fp32 accuracy.
#define CVT_PAIR(j, f0, f1)                                                     \
  { unsigned p0 = __float_as_uint(f0), p1 = __float_as_uint(f1);                \
    H.u[j] = (p1 & 0xFFFF0000u) | (p0 >> 16);                                   \
    unsigned q0 = __float_as_uint((f0) - __uint_as_float(p0 & 0xFFFF0000u));    \
    unsigned q1 = __float_as_uint((f1) - __uint_as_float(p1 & 0xFFFF0000u));    \
    L.u[j] = (q1 & 0xFFFF0000u) | (q0 >> 16); }

__device__ __forceinline__ void cvt_hl(const float4 a, const float4 b,
                                       short8& hi, short8& lo) {
  union { unsigned u[4]; short8 s; } H, L;
  CVT_PAIR(0, a.x, a.y)
  CVT_PAIR(1, a.z, a.w)
  CVT_PAIR(2, b.x, b.y)
  CVT_PAIR(3, b.z, b.w)
  hi = H.s; lo = L.s;
}

// ============ K0: hc_fn fp32 -> bf16 hi/lo (once per launch; B is block-invariant). ============
__launch_bounds__(256, 4)
__global__ void mhc_convb(const float* __restrict__ hc_fn,
                          unsigned short* __restrict__ bh,
                          unsigned short* __restrict__ bl) {
  const int g = blockIdx.x * 256 + threadIdx.x;     // float4 index, < 24576
  const float4 v = ((const float4*)hc_fn)[g];
  ushort4 h, l;
  unsigned p;
  p = __float_as_uint(v.x); h.x = p >> 16; l.x = __float_as_uint(v.x - __uint_as_float(p & 0xFFFF0000u)) >> 16;
  p = __float_as_uint(v.y); h.y = p >> 16; l.y = __float_as_uint(v.y - __uint_as_float(p & 0xFFFF0000u)) >> 16;
  p = __float_as_uint(v.z); h.z = p >> 16; l.z = __float_as_uint(v.z - __uint_as_float(p & 0xFFFF0000u)) >> 16;
  p = __float_as_uint(v.w); h.w = p >> 16; l.w = __float_as_uint(v.w - __uint_as_float(p & 0xFFFF0000u)) >> 16;
  ((ushort4*)bh)[g] = h;
  ((ushort4*)bl)[g] = l;
}

// ============ K1: LDS-staged MFMA partial GEMM, swizzled LDS, pre-cvt B. ============
// Block: 16 tokens x 512 K (32 KB LDS -> ~5 blocks/CU). Wave = K-quarter (128), 4 steps.
// LDS swizzle (rule #21, both-sides): linear gload_lds dest; SOURCE col4 ^= (token&7);
// A-read applies the same XOR -> 8 rows spread over 32 banks (was 16-way conflict, R15).
__launch_bounds__(256, 2)
__global__ void mhc_dots_mfma(const float* __restrict__ x,
                              const unsigned short* __restrict__ bh,
                              const unsigned short* __restrict__ bl,
                              float* __restrict__ wp, int ntok) {
  __shared__ float xs[TOK_B * KCH];    // 32 KB
  const int tid  = threadIdx.x;
  const int lane = tid & 63;
  const int wave = tid >> 6;
  const int mt = blockIdx.x >> 3;      // token-tile index
  const int kc = blockIdx.x & 7;       // K-chunk index
  const long long tok0 = (long long)mt * TOK_B;
  const int k0 = kc * KCH;

  // ---- stage 32 KB: 8 chunks, linear LDS dest + inverse-swizzled global source ----
  #pragma unroll
  for (int c = 0; c < 8; ++c) {
    const int S = c * 256 + wave * 64;          // wave-uniform float4 slot base
    const int t = S >> 7;                       // token row (uniform per wave-chunk)
    const int c4src = (((wave & 1) * 64 + lane) ^ (t & 7));
    gload_lds16(x + (tok0 + t) * DDIM + k0 + c4src * 4, xs + (size_t)S * 4);
  }

  const int kh  = wave;                // K-quarter (128 floats)
  const int row = lane & 15;           // A row (token) / B col (m) / C col
  const int ks  = lane >> 4;           // k-slice (8 elems)

  // B fragment pointers (bf16 hi/lo, L2-hot, zero cvt at use)
  const unsigned short* bp0h = bh + (long long)row * DDIM + k0 + kh * 128 + ks * 8;
  const unsigned short* bp0l = bl + (long long)row * DDIM + k0 + kh * 128 + ks * 8;
  const int fr1c = (row < 8) ? (16 + row) : 23;
  const unsigned short* bp1h = bh + (long long)fr1c * DDIM + k0 + kh * 128 + ks * 8;
  const unsigned short* bp1l = bl + (long long)fr1c * DDIM + k0 + kh * 128 + ks * 8;
  const bool v1 = (row < 8);
  const short8 z8 = {0, 0, 0, 0, 0, 0, 0, 0};

  f32x4 acc0 = {0.f, 0.f, 0.f, 0.f};
  f32x4 acc1 = {0.f, 0.f, 0.f, 0.f};
  float ssq = 0.f;

  // B 1-deep prefetch (4 x short8 payload = 16 VGPR)
  short8 b0h_c = *(const short8*)bp0h;
  short8 b0l_c = *(const short8*)bp0l;
  short8 b1h_c = v1 ? *(const short8*)bp1h : z8;
  short8 b1l_c = v1 ? *(const short8*)bp1l : z8;

  __syncthreads();                     // drains staging vmcnt

  const int rsw = row & 7;             // read-side swizzle key
  const float* arow = xs + (size_t)row * KCH;

  #pragma unroll
  for (int s = 0; s < 4; ++s) {        // 4 K-steps of 32
    short8 b0h_n, b0l_n, b1h_n, b1l_n;
    if (s < 3) {
      const int o = (s + 1) * 32;
      b0h_n = *(const short8*)(bp0h + o);
      b0l_n = *(const short8*)(bp0l + o);
      b1h_n = v1 ? *(const short8*)(bp1h + o) : z8;
      b1l_n = v1 ? *(const short8*)(bp1l + o) : z8;
    }
    const int c4 = kh * 32 + s * 8 + ks * 2;
    const float4 a0 = *(const float4*)(arow + (size_t)(c4 ^ rsw) * 4);
    const float4 a1 = *(const float4*)(arow + (size_t)((c4 + 1) ^ rsw) * 4);

    ssq = fmaf(a0.x, a0.x, fmaf(a0.y, a0.y, fmaf(a0.z, a0.z, fmaf(a0.w, a0.w, ssq))));
    ssq = fmaf(a1.x, a1.x, fmaf(a1.y, a1.y, fmaf(a1.z, a1.z, fmaf(a1.w, a1.w, ssq))));

    short8 ahi, alo;
    cvt_hl(a0, a1, ahi, alo);

    acc0 = __builtin_amdgcn_mfma_f32_16x16x32_bf16(ahi, b0h_c, acc0, 0, 0, 0);
    acc1 = __builtin_amdgcn_mfma_f32_16x16x32_bf16(ahi, b1h_c, acc1, 0, 0, 0);
    acc0 = __builtin_amdgcn_mfma_f32_16x16x32_bf16(ahi, b0l_c, acc0, 0, 0, 0);
    acc1 = __builtin_amdgcn_mfma_f32_16x16x32_bf16(ahi, b1l_c, acc1, 0, 0, 0);
    acc0 = __builtin_amdgcn_mfma_f32_16x16x32_bf16(alo, b0h_c, acc0, 0, 0, 0);
    acc1 = __builtin_amdgcn_mfma_f32_16x16x32_bf16(alo, b1h_c, acc1, 0, 0, 0);

    if (s < 3) {
      b0h_c = b0h_n; b0l_c = b0l_n;
      b1h_c = b1h_n; b1l_c = b1l_n;
    }
  }

  // ssq: lanes l, l^16, l^32, l^48 share a row -> combine the 4 k-slices
  ssq += __shfl_xor(ssq, 16, 64);
  ssq += __shfl_xor(ssq, 32, 64);

  // direct partial stores: wp[ps][tok][25], ps = kc*4 + kh
  const int ps = kc * 4 + kh;
  float* wpk = wp + (long long)ps * ntok * 25;
  if (lane < 16) wpk[(tok0 + lane) * 25 + 24] = ssq;
  const int rq = lane >> 4;
  #pragma unroll
  for (int r = 0; r < 4; ++r)
    wpk[(tok0 + rq * 4 + r) * 25 + row] = acc0[r];
  if (row < 8) {
    #pragma unroll
    for (int r = 0; r < 4; ++r)
      wpk[(tok0 + rq * 4 + r) * 25 + 16 + row] = acc1[r];
  }
}

// ============ K1b: reduce 32 partial sets + sinkhorn -> gates[tok][24]. ============
__launch_bounds__(256, 4)
__global__ void mhc_sinkhorn(const float* __restrict__ wp,
                             const float* __restrict__ hc_scale,
                             const float* __restrict__ hc_base,
                             float* __restrict__ gates, int ntok) {
  const int lane = threadIdx.x & 63;
  const int wave = threadIdx.x >> 6;
  const long long tok = (long long)blockIdx.x * 16 + wave * 4 + (lane >> 4);
  const int e = lane & 15;             // i*4 + j

  const long long kstride = (long long)ntok * 25;
  const float* b = wp + tok * 25;
  float sres = 0.f, ssq = 0.f, spre = 0.f, spost = 0.f;
  #pragma unroll 4
  for (int ps = 0; ps < NPS; ++ps) {
    const float* p = b + ps * kstride;
    sres += p[8 + e];
    ssq  += p[24];
    if (e < NS) { spre += p[e]; spost += p[NS + e]; }
  }

  const float rs = rsqrtf(ssq * (1.0f / DDIM) + NORM_EPS_F);
  const float s0 = hc_scale[0], s1 = hc_scale[1], s2 = hc_scale[2];

  float h = sres * rs * s2 + hc_base[8 + e];
  float mx = fmaxf(h, __shfl_xor(h, 1, 4));
  mx = fmaxf(mx, __shfl_xor(mx, 2, 4));
  float ex = expf(h - mx);
  float sm = ex + __shfl_xor(ex, 1, 4);
  sm += __shfl_xor(sm, 2, 4);
  h = ex * frcp(sm) + HC_EPS_F;
  float cs = h + __shfl_xor(h, 4, 16);
  cs += __shfl_xor(cs, 8, 16);
  h *= frcp(cs + HC_EPS_F);
  #pragma unroll 1
  for (int itn = 0; itn < 19; ++itn) {
    float rsum = h + __shfl_xor(h, 1, 4);
    rsum += __shfl_xor(rsum, 2, 4);
    h *= frcp(rsum + HC_EPS_F);
    float csum = h + __shfl_xor(h, 4, 16);
    csum += __shfl_xor(csum, 8, 16);
    h *= frcp(csum + HC_EPS_F);
  }
  float* g = gates + tok * 24;
  g[8 + e] = h;
  if (e < NS) {
    g[e] = frcp(1.0f + expf(-(spre * rs * s0 + hc_base[e]))) + HC_EPS_F;
    g[NS + e] = 2.0f * frcp(1.0f + expf(-(spost * rs * s1 + hc_base[NS + e])));
  }
}

// ============ K2: gates + x -> out (pure stream, at write roofline ~21us) ============
__launch_bounds__(256, 8)
__global__ void mhc_out(const float* __restrict__ x,
                        const float* __restrict__ gates,
                        float* __restrict__ out) {
  const long long token = blockIdx.x;
  const int q = threadIdx.x;           // float4 index in [0,256)

  const float* g = gates + token * 24; // uniform address -> scalar loads
  float hp[NS], hq[NS], hr[NS][NS];
  #pragma unroll
  for (int i = 0; i < NS; ++i) {
    hp[i] = g[i];
    hq[i] = g[NS + i];
    #pragma unroll
    for (int j = 0; j < NS; ++j) hr[i][j] = g[8 + i * NS + j];
  }

  const float4* xb = (const float4*)(x + token * DDIM);
  float4 xv[NS];
  #pragma unroll
  for (int i = 0; i < NS; ++i) xv[i] = xb[i * 256 + q];

  float4 y;
  y.x = hp[0]*xv[0].x + hp[1]*xv[1].x + hp[2]*xv[2].x + hp[3]*xv[3].x;
  y.y = hp[0]*xv[0].y + hp[1]*xv[1].y + hp[2]*xv[2].y + hp[3]*xv[3].y;
  y.z = hp[0]*xv[0].z + hp[1]*xv[1].z + hp[2]*xv[2].z + hp[3]*xv[3].z;
  y.w = hp[0]*xv[0].w + hp[1]*xv[1].w + hp[2]*xv[2].w + hp[3]*xv[3].w;

  float4* ob = (float4*)(out + token * DDIM);
  #pragma unroll
  for (int n = 0; n < NS; ++n) {
    float4 o;
    o.x = hq[n]*y.x + hr[0][n]*xv[0].x + hr[1][n]*xv[1].x + hr[2][n]*xv[2].x + hr[3][n]*xv[3].x;
    o.y = hq[n]*y.y + hr[0][n]*xv[0].y + hr[1][n]*xv[1].y + hr[2][n]*xv[2].y + hr[3][n]*xv[3].y;
    o.z = hq[n]*y.z + hr[0][n]*xv[0].z + hr[1][n]*xv[1].z + hr[2][n]*xv[2].z + hr[3][n]*xv[3].z;
    o.w = hq[n]*y.w + hr[0][n]*xv[0].w + hr[1][n]*xv[1].w + hr[2][n]*xv[2].w + hr[3][n]*xv[3].w;
    ob[n * 256 + q] = o;
  }
}

extern "C" void kernel_launch(void* const* d_in, const int* in_sizes, int n_in,
                              void* d_out, int out_size, void* d_ws, size_t ws_size,
                              hipStream_t stream) {
  const float* x        = (const float*)d_in[0];
  const float* hc_fn    = (const float*)d_in[1];
  const float* hc_scale = (const float*)d_in[2];
  const float* hc_base  = (const float*)d_in[3];
  float* out = (float*)d_out;

  const int ntok = in_sizes[0] / DDIM;       // B*S = 8192
  float* gates = (float*)d_ws;               // ntok*24*4 = 786 KB (PROVEN within ws_size)

  // out used as scratch (K2 fully overwrites it at the end):
  //   wp[32][ntok][25]      = 26.2 MB   at out + 0
  //   bh[24][4096] bf16     = 196 KB    at out + 32*ntok*25
  //   bl[24][4096] bf16     = 196 KB    after bh
  float* wp = out;
  unsigned short* bh = (unsigned short*)(out + (size_t)NPS * ntok * 25);
  unsigned short* bl = bh + 24 * DDIM;

  mhc_convb<<<(24 * DDIM / 4) / 256, 256, 0, stream>>>(hc_fn, bh, bl);
  mhc_dots_mfma<<<(ntok / TOK_B) * 8, 256, 0, stream>>>(x, bh, bl, wp, ntok);
  mhc_sinkhorn<<<ntok / 16, 256, 0, stream>>>(wp, hc_scale, hc_base, gates, ntok);
  mhc_out<<<ntok, 256, 0, stream>>>(x, gates, out);
}

// Round 17
// 96.879 us; speedup vs baseline: 1.0338x; 1.0338x over previous
//
#include <hip/hip_runtime.h>
#include <math.h>

#define NS 4
#define HDIM 1024
#define DDIM 4096           // NS*HDIM
#define TOK_B 16            // tokens per block (dots)
#define KCH 256             // K per chunk; 16 chunks cover K=4096
#define NCH 16
#define NPS 4               // partial sets = 4 kh quarters
#define HC_EPS_F 1e-6f
#define NORM_EPS_F 1e-6f

typedef __attribute__((ext_vector_type(8))) short short8;
typedef __attribute__((ext_vector_type(4))) float f32x4;

__device__ __forceinline__ float frcp(float v) { return __builtin_amdgcn_rcpf(v); }

__device__ __forceinline__ void gload_lds16(const float* g, float* l) {
  __builtin_amdgcn_global_load_lds(
      (const __attribute__((address_space(1))) void*)g,
      (__attribute__((address_space(3))) void*)l, 16, 0, 0);
}

// fp32 -> bf16 hi (truncate) + lo (residual). 3-term MFMA ~ fp32 accuracy.
#define CVT_PAIR(j, f0, f1)                                                     \
  { unsigned p0 = __float_as_uint(f0), p1 = __float_as_uint(f1);                \
    H.u[j] = (p1 & 0xFFFF0000u) | (p0 >> 16);                                   \
    unsigned q0 = __float_as_uint((f0) - __uint_as_float(p0 & 0xFFFF0000u));    \
    unsigned q1 = __float_as_uint((f1) - __uint_as_float(p1 & 0xFFFF0000u));    \
    L.u[j] = (q1 & 0xFFFF0000u) | (q0 >> 16); }

__device__ __forceinline__ void cvt_hl(const float4 a, const float4 b,
                                       short8& hi, short8& lo) {
  union { unsigned u[4]; short8 s; } H, L;
  CVT_PAIR(0, a.x, a.y)
  CVT_PAIR(1, a.z, a.w)
  CVT_PAIR(2, b.x, b.y)
  CVT_PAIR(3, b.z, b.w)
  hi = H.s; lo = L.s;
}

// ============ K0: hc_fn fp32 -> bf16 hi/lo (once; B is block-invariant). ============
__launch_bounds__(256, 4)
__global__ void mhc_convb(const float* __restrict__ hc_fn,
                          unsigned short* __restrict__ bh,
                          unsigned short* __restrict__ bl) {
  const int g = blockIdx.x * 256 + threadIdx.x;     // float4 index, < 24576
  const float4 v = ((const float4*)hc_fn)[g];
  ushort4 h, l;
  unsigned p;
  p = __float_as_uint(v.x); h.x = p >> 16; l.x = __float_as_uint(v.x - __uint_as_float(p & 0xFFFF0000u)) >> 16;
  p = __float_as_uint(v.y); h.y = p >> 16; l.y = __float_as_uint(v.y - __uint_as_float(p & 0xFFFF0000u)) >> 16;
  p = __float_as_uint(v.z); h.z = p >> 16; l.z = __float_as_uint(v.z - __uint_as_float(p & 0xFFFF0000u)) >> 16;
  p = __float_as_uint(v.w); h.w = p >> 16; l.w = __float_as_uint(v.w - __uint_as_float(p & 0xFFFF0000u)) >> 16;
  ((ushort4*)bh)[g] = h;
  ((ushort4*)bl)[g] = l;
}

// ============ K1: chunk-looped dbuf LDS MFMA dots. Block = 16 tok x FULL K. ============
// 16 chunks of 256 K; stage(kc+1) in flight while computing kc -> continuous HBM stream.
// acc persists across chunks -> only 4 partial sets (kh quarters).
__launch_bounds__(256, 2)
__global__ void mhc_dots_mfma(const float* __restrict__ x,
                              const unsigned short* __restrict__ bh,
                              const unsigned short* __restrict__ bl,
                              float* __restrict__ wp, int ntok) {
  __shared__ float xs[2][TOK_B * KCH]; // 2 x 16 KB double buffer
  const int tid  = threadIdx.x;
  const int lane = tid & 63;
  const int wave = tid >> 6;
  const long long tok0 = (long long)blockIdx.x * TOK_B;

  // stage chunk kcn into buffer d: 4 wave-uniform rows (t = c*4+wave), linear LDS,
  // source col4 ^= (t&7) (both-sides swizzle, rule #21; read undoes it)
#define STAGE(d, kcn)                                                           \
  {                                                                             \
    _Pragma("unroll")                                                           \
    for (int c = 0; c < 4; ++c) {                                               \
      const int t = c * 4 + wave;                                               \
      const int c4src = lane ^ (t & 7);                                         \
      gload_lds16(x + (tok0 + t) * DDIM + (kcn) * KCH + c4src * 4,              \
                  &xs[d][(c * 4 + wave) * KCH + lane * 4 - lane * 4 + (c * 256 + wave * 64) * 4]); \
    }                                                                           \
  }
  // NOTE: LDS slot S = c*256 + wave*64 (+lane implicit in gload); simplified below.
#undef STAGE
#define STAGE(d, kcn)                                                           \
  {                                                                             \
    _Pragma("unroll")                                                           \
    for (int c = 0; c < 4; ++c) {                                               \
      const int S = c * 256 + wave * 64;          /* float4 slot base */        \
      const int t = S >> 6;                       /* token row */               \
      const int c4src = lane ^ (t & 7);                                         \
      gload_lds16(x + (tok0 + t) * DDIM + (kcn) * KCH + c4src * 4,              \
                  &xs[d][(size_t)S * 4]);                                       \
    }                                                                           \
  }

  const int kh  = wave;                // K-quarter of each chunk (64 floats)
  const int row = lane & 15;           // A row (token) / B col (m) / C col
  const int ks  = lane >> 4;           // k-slice (8 elems)

  // B fragment bases (bf16 hi/lo, L2-hot)
  const unsigned short* bp0h = bh + (long long)row * DDIM + kh * 64 + ks * 8;
  const unsigned short* bp0l = bl + (long long)row * DDIM + kh * 64 + ks * 8;
  const int fr1c = (row < 8) ? (16 + row) : 23;
  const unsigned short* bp1h = bh + (long long)fr1c * DDIM + kh * 64 + ks * 8;
  const unsigned short* bp1l = bl + (long long)fr1c * DDIM + kh * 64 + ks * 8;
  const bool v1 = (row < 8);
  const short8 z8 = {0, 0, 0, 0, 0, 0, 0, 0};

  f32x4 acc0 = {0.f, 0.f, 0.f, 0.f};
  f32x4 acc1 = {0.f, 0.f, 0.f, 0.f};
  float ssq = 0.f;

  STAGE(0, 0)
  __syncthreads();                     // chunk 0 ready

  const int rsw = row & 7;             // read-side swizzle key
  const float* arow0 = xs[0] + (size_t)row * KCH;
  const float* arow1 = xs[1] + (size_t)row * KCH;

  for (int kc = 0; kc < NCH; ++kc) {
    if (kc < NCH - 1) {
      if (kc & 1) STAGE(0, kc + 1) else STAGE(1, kc + 1)
    }
    const float* arow = (kc & 1) ? arow1 : arow0;
    const int kb = kc * KCH;

    #pragma unroll
    for (int s = 0; s < 2; ++s) {      // 2 K-steps of 32 per chunk
      const int ko = kb + s * 32;
      const short8 b0h = *(const short8*)(bp0h + ko);
      const short8 b0l = *(const short8*)(bp0l + ko);
      const short8 b1h = v1 ? *(const short8*)(bp1h + ko) : z8;
      const short8 b1l = v1 ? *(const short8*)(bp1l + ko) : z8;

      const int c4 = kh * 16 + s * 8 + ks * 2;
      const float4 a0 = *(const float4*)(arow + (size_t)(c4 ^ rsw) * 4);
      const float4 a1 = *(const float4*)(arow + (size_t)((c4 + 1) ^ rsw) * 4);

      ssq = fmaf(a0.x, a0.x, fmaf(a0.y, a0.y, fmaf(a0.z, a0.z, fmaf(a0.w, a0.w, ssq))));
      ssq = fmaf(a1.x, a1.x, fmaf(a1.y, a1.y, fmaf(a1.z, a1.z, fmaf(a1.w, a1.w, ssq))));

      short8 ahi, alo;
      cvt_hl(a0, a1, ahi, alo);

      acc0 = __builtin_amdgcn_mfma_f32_16x16x32_bf16(ahi, b0h, acc0, 0, 0, 0);
      acc1 = __builtin_amdgcn_mfma_f32_16x16x32_bf16(ahi, b1h, acc1, 0, 0, 0);
      acc0 = __builtin_amdgcn_mfma_f32_16x16x32_bf16(ahi, b0l, acc0, 0, 0, 0);
      acc1 = __builtin_amdgcn_mfma_f32_16x16x32_bf16(ahi, b1l, acc1, 0, 0, 0);
      acc0 = __builtin_amdgcn_mfma_f32_16x16x32_bf16(alo, b0h, acc0, 0, 0, 0);
      acc1 = __builtin_amdgcn_mfma_f32_16x16x32_bf16(alo, b1h, acc1, 0, 0, 0);
    }
    __syncthreads();                   // next chunk staged; buf safe to overwrite
  }

  // ssq: lanes l, l^16, l^32 share row -> combine the 4 k-slices
  ssq += __shfl_xor(ssq, 16, 64);
  ssq += __shfl_xor(ssq, 32, 64);

  // direct partial stores: wp[kh][tok][25]
  float* wpk = wp + (long long)kh * ntok * 25;
  if (lane < 16) wpk[(tok0 + lane) * 25 + 24] = ssq;
  const int rq = lane >> 4;
  #pragma unroll
  for (int r = 0; r < 4; ++r)
    wpk[(tok0 + rq * 4 + r) * 25 + row] = acc0[r];
  if (row < 8) {
    #pragma unroll
    for (int r = 0; r < 4; ++r)
      wpk[(tok0 + rq * 4 + r) * 25 + 16 + row] = acc1[r];
  }
#undef STAGE
}

// ============ K1b: reduce 4 partial sets + sinkhorn -> gates[tok][24]. ============
__launch_bounds__(256, 4)
__global__ void mhc_sinkhorn(const float* __restrict__ wp,
                             const float* __restrict__ hc_scale,
                             const float* __restrict__ hc_base,
                             float* __restrict__ gates, int ntok) {
  const int lane = threadIdx.x & 63;
  const int wave = threadIdx.x >> 6;
  const long long tok = (long long)blockIdx.x * 16 + wave * 4 + (lane >> 4);
  const int e = lane & 15;             // i*4 + j

  const long long kstride = (long long)ntok * 25;
  const float* b = wp + tok * 25;
  float sres = 0.f, ssq = 0.f, spre = 0.f, spost = 0.f;
  #pragma unroll
  for (int ps = 0; ps < NPS; ++ps) {
    const float* p = b + ps * kstride;
    sres += p[8 + e];
    ssq  += p[24];
    if (e < NS) { spre += p[e]; spost += p[NS + e]; }
  }

  const float rs = rsqrtf(ssq * (1.0f / DDIM) + NORM_EPS_F);
  const float s0 = hc_scale[0], s1 = hc_scale[1], s2 = hc_scale[2];

  float h = sres * rs * s2 + hc_base[8 + e];
  float mx = fmaxf(h, __shfl_xor(h, 1, 4));
  mx = fmaxf(mx, __shfl_xor(mx, 2, 4));
  float ex = expf(h - mx);
  float sm = ex + __shfl_xor(ex, 1, 4);
  sm += __shfl_xor(sm, 2, 4);
  h = ex * frcp(sm) + HC_EPS_F;
  float cs = h + __shfl_xor(h, 4, 16);
  cs += __shfl_xor(cs, 8, 16);
  h *= frcp(cs + HC_EPS_F);
  #pragma unroll 1
  for (int itn = 0; itn < 19; ++itn) {
    float rsum = h + __shfl_xor(h, 1, 4);
    rsum += __shfl_xor(rsum, 2, 4);
    h *= frcp(rsum + HC_EPS_F);
    float csum = h + __shfl_xor(h, 4, 16);
    csum += __shfl_xor(csum, 8, 16);
    h *= frcp(csum + HC_EPS_F);
  }
  float* g = gates + tok * 24;
  g[8 + e] = h;
  if (e < NS) {
    g[e] = frcp(1.0f + expf(-(spre * rs * s0 + hc_base[e]))) + HC_EPS_F;
    g[NS + e] = 2.0f * frcp(1.0f + expf(-(spost * rs * s1 + hc_base[NS + e])));
  }
}

// ============ K2: gates + x -> out (pure stream, at write roofline ~21us) ============
__launch_bounds__(256, 8)
__global__ void mhc_out(const float* __restrict__ x,
                        const float* __restrict__ gates,
                        float* __restrict__ out) {
  const long long token = blockIdx.x;
  const int q = threadIdx.x;           // float4 index in [0,256)

  const float* g = gates + token * 24; // uniform address -> scalar loads
  float hp[NS], hq[NS], hr[NS][NS];
  #pragma unroll
  for (int i = 0; i < NS; ++i) {
    hp[i] = g[i];
    hq[i] = g[NS + i];
    #pragma unroll
    for (int j = 0; j < NS; ++j) hr[i][j] = g[8 + i * NS + j];
  }

  const float4* xb = (const float4*)(x + token * DDIM);
  float4 xv[NS];
  #pragma unroll
  for (int i = 0; i < NS; ++i) xv[i] = xb[i * 256 + q];

  float4 y;
  y.x = hp[0]*xv[0].x + hp[1]*xv[1].x + hp[2]*xv[2].x + hp[3]*xv[3].x;
  y.y = hp[0]*xv[0].y + hp[1]*xv[1].y + hp[2]*xv[2].y + hp[3]*xv[3].y;
  y.z = hp[0]*xv[0].z + hp[1]*xv[1].z + hp[2]*xv[2].z + hp[3]*xv[3].z;
  y.w = hp[0]*xv[0].w + hp[1]*xv[1].w + hp[2]*xv[2].w + hp[3]*xv[3].w;

  float4* ob = (float4*)(out + token * DDIM);
  #pragma unroll
  for (int n = 0; n < NS; ++n) {
    float4 o;
    o.x = hq[n]*y.x + hr[0][n]*xv[0].x + hr[1][n]*xv[1].x + hr[2][n]*xv[2].x + hr[3][n]*xv[3].x;
    o.y = hq[n]*y.y + hr[0][n]*xv[0].y + hr[1][n]*xv[1].y + hr[2][n]*xv[2].y + hr[3][n]*xv[3].y;
    o.z = hq[n]*y.z + hr[0][n]*xv[0].z + hr[1][n]*xv[1].z + hr[2][n]*xv[2].z + hr[3][n]*xv[3].z;
    o.w = hq[n]*y.w + hr[0][n]*xv[0].w + hr[1][n]*xv[1].w + hr[2][n]*xv[2].w + hr[3][n]*xv[3].w;
    ob[n * 256 + q] = o;
  }
}

extern "C" void kernel_launch(void* const* d_in, const int* in_sizes, int n_in,
                              void* d_out, int out_size, void* d_ws, size_t ws_size,
                              hipStream_t stream) {
  const float* x        = (const float*)d_in[0];
  const float* hc_fn    = (const float*)d_in[1];
  const float* hc_scale = (const float*)d_in[2];
  const float* hc_base  = (const float*)d_in[3];
  float* out = (float*)d_out;

  const int ntok = in_sizes[0] / DDIM;       // B*S = 8192
  float* gates = (float*)d_ws;               // ntok*24*4 = 786 KB (PROVEN within ws_size)

  // out used as scratch (K2 fully overwrites it last):
  //   wp[4][ntok][25]   = 3.3 MB  at out+0
  //   bh/bl bf16        = 2x196 KB after wp
  float* wp = out;
  unsigned short* bh = (unsigned short*)(out + (size_t)NPS * ntok * 25);
  unsigned short* bl = bh + 24 * DDIM;

  mhc_convb<<<(24 * DDIM / 4) / 256, 256, 0, stream>>>(hc_fn, bh, bl);
  mhc_dots_mfma<<<ntok / TOK_B, 256, 0, stream>>>(x, bh, bl, wp, ntok);
  mhc_sinkhorn<<<ntok / 16, 256, 0, stream>>>(wp, hc_scale, hc_base, gates, ntok);
  mhc_out<<<ntok, 256, 0, stream>>>(x, gates, out);
}